// Round 2
// baseline (1156.319 us; speedup 1.0000x reference)
//
#include <hip/hip_runtime.h>
#include <hip/hip_bf16.h>

typedef short short8 __attribute__((ext_vector_type(8)));
typedef short short4v __attribute__((ext_vector_type(4)));
typedef float f32x4 __attribute__((ext_vector_type(4)));
typedef __bf16 bf16x8 __attribute__((ext_vector_type(8)));

#define DEVI static __device__ __forceinline__

#if __has_builtin(__builtin_amdgcn_exp2f)
#define EXP2(x) __builtin_amdgcn_exp2f(x)
#else
#define EXP2(x) exp2f(x)
#endif
#if __has_builtin(__builtin_amdgcn_rcpf)
#define RCP(x) __builtin_amdgcn_rcpf(x)
#else
#define RCP(x) (1.0f / (x))
#endif

static constexpr int BB = 256, TT = 512, DIN0 = 40, HH = 128, NCLS = 7;
static constexpr int NB = 16;     // batch rows per workgroup
static constexpr int NTHR = 512;  // 8 waves
static constexpr float L2E = 1.44269504088896f;

DEVI short f2b(float x) {
  union { __hip_bfloat16 h; short s; } u;
  u.h = __float2bfloat16(x);
  return u.s;
}

DEVI bf16x8 as_bf(short8 s) { return __builtin_bit_cast(bf16x8, s); }

// Barrier with ONLY lgkmcnt drain: global stores/loads in flight cross the
// barrier freely (the __syncthreads() vmcnt(0) drain was ~2x 300-600 cyc of
// per-step stall on the recurrent chain). sched_barrier(0) per rule #18.
DEVI void bar_lgkm() {
  asm volatile("s_waitcnt lgkmcnt(0)" ::: "memory");
  __builtin_amdgcn_s_barrier();
  __builtin_amdgcn_sched_barrier(0);
}

// One WG = (direction, 16-batch tile). W held as bf16 MFMA A-fragments in
// registers for all 512 steps. Per step: acc (pre-filled with bias + x-part
// at the END of the previous step) += W_hh @ h_{t-1} via 4 chained
// mfma_f32_16x16x32_bf16 per gate block, then the fp32 cell update.
// Wave w owns rows [16w,16w+16) of each gate block i/f/g/o, so each lane has
// the 4 gates of its 4 cells locally (C/D: col=lane&15, row=(lane>>4)*4+r).
// x is staged 2 steps ahead (global load -> regs -> LDS one step later), so
// no vmem wait ever lands on the critical path.
template <bool IS_L0>
__global__ __launch_bounds__(NTHR, 2) void lstm2(
    const float* __restrict__ x0, const short* __restrict__ h1_in,
    const float* __restrict__ Wih_f, const float* __restrict__ Whh_f,
    const float* __restrict__ bias_f, const float* __restrict__ Wih_r,
    const float* __restrict__ Whh_r, const float* __restrict__ bias_r,
    short* __restrict__ h1_out, float* __restrict__ h2last) {
  constexpr int K0 = IS_L0 ? 64 : 256;    // padded x-part of K
  constexpr int DI = IS_L0 ? DIN0 : 256;  // real x dim
  constexpr int KFX = K0 / 32;            // x k-fragments (2 / 8)
  constexpr int KFH = HH / 32;            // h k-fragments (4)
  constexpr int RSH = 136;                // Hb row stride (shorts): 272B, bank-spread
  constexpr int XROWB_L0 = 144;           // L0 Xb row stride bytes (72 shorts)
  constexpr int XBUF = IS_L0 ? (16 * XROWB_L0) : 8192;  // bytes per x buffer

  __shared__ short Hb[2][NB][RSH];
  __shared__ char Xraw[2 * XBUF];

  const int tid = threadIdx.x;
  const int w = tid >> 6;
  const int lane = tid & 63;
  const int lg = lane >> 4;
  const int bcol = lane & 15;
  const int dir = blockIdx.x & 1;
  const int b0 = (blockIdx.x >> 1) * NB;

  const float* __restrict__ Wih = dir ? Wih_r : Wih_f;
  const float* __restrict__ Whh = dir ? Whh_r : Whh_f;
  const float* __restrict__ bias = dir ? bias_r : bias_f;

  auto tmap = [&](int s) { return dir ? (TT - 1 - s) : s; };

  // ---- W fragments, register-resident for the whole kernel ----
  // A-frag (16x16x32): row m = lane&15, k = (lane>>4)*8 + e.
  // Pre-scale: i,f,o by -log2e (sigmoid via exp2), g by +2*log2e (tanh via exp2).
  short8 wx[4][KFX];  // x-part (W_ih, zero-padded to K0)
  short8 wh[4][KFH];  // h-part (W_hh)
#pragma unroll
  for (int q = 0; q < 4; ++q) {
    const float scale = (q == 2) ? (2.0f * L2E) : (-L2E);
    const int m = q * HH + w * 16 + bcol;
#pragma unroll
    for (int kk = 0; kk < KFX; ++kk) {
      short8 f;
#pragma unroll
      for (int e = 0; e < 8; ++e) {
        const int k = kk * 32 + lg * 8 + e;
        float v = (k < DI) ? Wih[(size_t)m * DI + k] : 0.0f;
        f[e] = f2b(v * scale);
      }
      wx[q][kk] = f;
    }
#pragma unroll
    for (int kk = 0; kk < KFH; ++kk) {
      short8 f;
#pragma unroll
      for (int e = 0; e < 8; ++e)
        f[e] = f2b(Whh[(size_t)m * HH + kk * 32 + lg * 8 + e] * scale);
      wh[q][kk] = f;
    }
  }

  f32x4 bq[4];
#pragma unroll
  for (int q = 0; q < 4; ++q) {
    const float scale = (q == 2) ? (2.0f * L2E) : (-L2E);
#pragma unroll
    for (int r = 0; r < 4; ++r)
      bq[q][r] = bias[q * HH + w * 16 + lg * 4 + r] * scale;
  }

  // ---- zero LDS (h_{-1}=0; L0 x pad cols must be 0) ----
  for (int i = tid; i < (int)(2 * NB * RSH * 2) / 4; i += NTHR)
    ((int*)&Hb[0][0][0])[i] = 0;
  for (int i = tid; i < (int)(2 * XBUF) / 4; i += NTHR) ((int*)Xraw)[i] = 0;
  __syncthreads();

  // x B-frag read: lane needs X[k=32kk+8lg..+7][col=bcol].
  // L1: linear [16][256] bf16 rows with XOR swizzle (applied identically on
  // the staged global source offset) -> ds_read_b128 at the 8-cycle floor.
  auto ldx = [&](int p, int kk) -> short8 {
    if constexpr (IS_L0) {
      return *(const short8*)(Xraw + p * XBUF + bcol * XROWB_L0 + kk * 64 + lg * 16);
    } else {
      int byte = ((bcol << 9) + (kk << 6) + (lg << 4)) ^ ((bcol & 7) << 4);
      return *(const short8*)(Xraw + p * XBUF + byte);
    }
  };

  // ---- staging state ----
  const int xr0 = tid / 10, c40 = tid % 10;  // L0: 160 staging threads
  // L1: thread tid owns LDS bytes [16*tid,16*tid+16); swizzled global source:
  const int o_swz = (tid << 4) ^ (((tid >> 5) & 7) << 4);
  const int xr1 = tid >> 5;          // L1 staging row (batch)
  const int xcb = o_swz & 511;       // L1 source byte within row
  f32x4 xstage_f = {0.f, 0.f, 0.f, 0.f};
  short8 xstage_h = {0, 0, 0, 0, 0, 0, 0, 0};

  // ---- prologue: stage x(0)->X[0], x(1)->X[1]; preload x(2) into regs ----
  if constexpr (IS_L0) {
    if (tid < 160) {
#pragma unroll
      for (int p = 0; p < 2; ++p) {
        f32x4 v = *(const f32x4*)(x0 + ((size_t)(b0 + xr0) * TT + tmap(p)) * DI + c40 * 4);
        short4v o4;
        o4[0] = f2b(v[0]); o4[1] = f2b(v[1]); o4[2] = f2b(v[2]); o4[3] = f2b(v[3]);
        *(short4v*)(Xraw + p * XBUF + xr0 * XROWB_L0 + c40 * 8) = o4;
      }
      xstage_f = *(const f32x4*)(x0 + ((size_t)(b0 + xr0) * TT + tmap(2)) * DI + c40 * 4);
    }
  } else {
#pragma unroll
    for (int p = 0; p < 2; ++p) {
      short8 v = *(const short8*)((const char*)h1_in +
                  ((((size_t)(b0 + xr1)) * TT + tmap(p)) << 9) + xcb);
      *(short8*)(Xraw + p * XBUF + tid * 16) = v;
    }
    xstage_h = *(const short8*)((const char*)h1_in +
                ((((size_t)(b0 + xr1)) * TT + tmap(2)) << 9) + xcb);
  }
  __syncthreads();

  // prefill acc for s=0: bias + x(0) projection
  f32x4 acc[4] = {bq[0], bq[1], bq[2], bq[3]};
#pragma unroll
  for (int kk = 0; kk < KFX; ++kk) {
    const bf16x8 bx = as_bf(ldx(0, kk));
#pragma unroll
    for (int q = 0; q < 4; ++q)
      acc[q] = __builtin_amdgcn_mfma_f32_16x16x32_bf16(as_bf(wx[q][kk]), bx, acc[q], 0, 0, 0);
  }
  __syncthreads();  // X[0] readers done; body(0) may overwrite X[0]

  f32x4 cst = {0.f, 0.f, 0.f, 0.f};
  const int j0 = w * 16 + lg * 4;

  for (int s = 0; s < TT; ++s) {
    const int cur = s & 1;

    // ---- stage x_{s+2} into X[cur] (regs loaded one full step ago -> the
    // implicit vmcnt wait is free); issue load of x_{s+3} ----
    if constexpr (IS_L0) {
      if (tid < 160) {
        if (s + 2 < TT) {
          short4v o4;
          o4[0] = f2b(xstage_f[0]); o4[1] = f2b(xstage_f[1]);
          o4[2] = f2b(xstage_f[2]); o4[3] = f2b(xstage_f[3]);
          *(short4v*)(Xraw + cur * XBUF + xr0 * XROWB_L0 + c40 * 8) = o4;
        }
        if (s + 3 < TT)
          xstage_f = *(const f32x4*)(x0 + ((size_t)(b0 + xr0) * TT + tmap(s + 3)) * DI + c40 * 4);
      }
    } else {
      if (s + 2 < TT) *(short8*)(Xraw + cur * XBUF + tid * 16) = xstage_h;
      if (s + 3 < TT)
        xstage_h = *(const short8*)((const char*)h1_in +
                    ((((size_t)(b0 + xr1)) * TT + tmap(s + 3)) << 9) + xcb);
    }

    // ---- recurrent part: acc += W_hh @ h_{s-1} (4-deep chain per gate) ----
#pragma unroll
    for (int kk = 0; kk < KFH; ++kk) {
      const bf16x8 bh = as_bf(*(const short8*)&Hb[cur][bcol][kk * 32 + lg * 8]);
#pragma unroll
      for (int q = 0; q < 4; ++q)
        acc[q] = __builtin_amdgcn_mfma_f32_16x16x32_bf16(as_bf(wh[q][kk]), bh, acc[q], 0, 0, 0);
    }

    // ---- cell update (fp32): sigmoid/tanh via exp2 on pre-scaled gates ----
    short4v hp;
    f32x4 hf;
#pragma unroll
    for (int r = 0; r < 4; ++r) {
      const float ig = RCP(1.0f + EXP2(acc[0][r]));
      const float fg = RCP(1.0f + EXP2(acc[1][r]));
      float tg = EXP2(acc[2][r]);
      tg = 1.0f - 2.0f * RCP(tg + 1.0f);
      const float og = RCP(1.0f + EXP2(acc[3][r]));
      const float cn = fg * cst[r] + ig * tg;
      cst[r] = cn;
      float tc = EXP2(cn * (2.0f * L2E));
      tc = 1.0f - 2.0f * RCP(tc + 1.0f);
      const float hv = og * tc;
      hf[r] = hv;
      hp[r] = f2b(hv);
    }
    *(short4v*)&Hb[cur ^ 1][bcol][j0] = hp;  // h_s for step s+1

    if constexpr (IS_L0) {
      // h1[b][t][dir*128 + j] (bf16) for layer 1; store flies, never drained
      *(short4v*)(h1_out + (((size_t)(b0 + bcol) * TT + tmap(s)) * 256) + dir * HH + j0) = hp;
    } else {
      if ((dir == 0 && s == TT - 1) || (dir == 1 && s == 0))
        *(f32x4*)(h2last + (size_t)(b0 + bcol) * 256 + dir * HH + j0) = hf;
    }

    // ---- prefill acc for step s+1: bias + x_{s+1} projection (off the
    // recurrent chain; x_{s+1} was LDS-written during step s-1) ----
    if (s + 1 < TT) {
      f32x4 a0 = bq[0], a1 = bq[1], a2 = bq[2], a3 = bq[3];
#pragma unroll
      for (int kk = 0; kk < KFX; ++kk) {
        const bf16x8 bx = as_bf(ldx(cur ^ 1, kk));
        a0 = __builtin_amdgcn_mfma_f32_16x16x32_bf16(as_bf(wx[0][kk]), bx, a0, 0, 0, 0);
        a1 = __builtin_amdgcn_mfma_f32_16x16x32_bf16(as_bf(wx[1][kk]), bx, a1, 0, 0, 0);
        a2 = __builtin_amdgcn_mfma_f32_16x16x32_bf16(as_bf(wx[2][kk]), bx, a2, 0, 0, 0);
        a3 = __builtin_amdgcn_mfma_f32_16x16x32_bf16(as_bf(wx[3][kk]), bx, a3, 0, 0, 0);
      }
      acc[0] = a0; acc[1] = a1; acc[2] = a2; acc[3] = a3;
    }

    bar_lgkm();
  }
}

__global__ void fc_kernel(const float* __restrict__ h2last,
                          const float* __restrict__ fcw,
                          const float* __restrict__ fcb,
                          float* __restrict__ out) {
  const int gid = blockIdx.x * blockDim.x + threadIdx.x;
  if (gid >= BB * NCLS) return;
  const int b = gid / NCLS, n = gid % NCLS;
  const float* hp = h2last + (size_t)b * 256;
  const float* wp = fcw + (size_t)n * 256;
  float s = fcb[n];
#pragma unroll 8
  for (int j = 0; j < 256; ++j) s = fmaf(hp[j], wp[j], s);
  out[gid] = s;
}

extern "C" void kernel_launch(void* const* d_in, const int* in_sizes, int n_in,
                              void* d_out, int out_size, void* d_ws, size_t ws_size,
                              hipStream_t stream) {
  const float* x     = (const float*)d_in[0];
  const float* Wih0f = (const float*)d_in[1];
  const float* Whh0f = (const float*)d_in[2];
  const float* b0f   = (const float*)d_in[3];
  const float* Wih0r = (const float*)d_in[4];
  const float* Whh0r = (const float*)d_in[5];
  const float* b0r   = (const float*)d_in[6];
  const float* Wih1f = (const float*)d_in[7];
  const float* Whh1f = (const float*)d_in[8];
  const float* b1f   = (const float*)d_in[9];
  const float* Wih1r = (const float*)d_in[10];
  const float* Whh1r = (const float*)d_in[11];
  const float* b1r   = (const float*)d_in[12];
  const float* fcw   = (const float*)d_in[13];
  const float* fcb   = (const float*)d_in[14];

  short* h1 = (short*)d_ws;                                           // [B][T][256] bf16, 64 MB
  float* h2last = (float*)((char*)d_ws + (size_t)BB * TT * 256 * 2);  // [B][256] f32

  lstm2<true><<<dim3(32), dim3(NTHR), 0, stream>>>(
      x, nullptr, Wih0f, Whh0f, b0f, Wih0r, Whh0r, b0r, h1, nullptr);
  lstm2<false><<<dim3(32), dim3(NTHR), 0, stream>>>(
      nullptr, h1, Wih1f, Whh1f, b1f, Wih1r, Whh1r, b1r, nullptr, h2last);
  fc_kernel<<<dim3((BB * NCLS + 255) / 256), dim3(256), 0, stream>>>(
      h2last, fcw, fcb, (float*)d_out);
}